// Round 2
// baseline (828.733 us; speedup 1.0000x reference)
//
#include <hip/hip_runtime.h>
#include <hip/hip_fp16.h>

typedef __attribute__((ext_vector_type(8))) _Float16 f16x8;
typedef __attribute__((ext_vector_type(8))) unsigned short u16x8;
typedef __attribute__((ext_vector_type(4))) float f32x4;

#define DEV __device__ __forceinline__

DEV unsigned short f2h(float f) {
  _Float16 h = (_Float16)f;
  return __builtin_bit_cast(unsigned short, h);
}

#if __has_builtin(__builtin_amdgcn_fdot2)
typedef __attribute__((ext_vector_type(2))) _Float16 f16x2;
DEV float fdot2u(unsigned a, unsigned b, float c) {
  return __builtin_amdgcn_fdot2(__builtin_bit_cast(f16x2, a),
                                __builtin_bit_cast(f16x2, b), c, false);
}
#else
DEV float fdot2u(unsigned a, unsigned b, float c) {
  __half2 ha = __builtin_bit_cast(__half2, a);
  __half2 hb = __builtin_bit_cast(__half2, b);
  return c + __low2float(ha) * __low2float(hb) + __high2float(ha) * __high2float(hb);
}
#endif

// ---------------------------------------------------------------- mask canon
__global__ __launch_bounds__(256) void k_mask(const unsigned* __restrict__ raw,
                                              int* __restrict__ canon) {
  __shared__ int s_gt1, s_f32;
  int t = threadIdx.x;
  if (t == 0) { s_gt1 = 0; s_f32 = 0; }
  __syncthreads();
  int gt1 = 0, fv = 0;
  for (int i = t; i < 512; i += 256) {
    unsigned v = raw[i];
    if (v == 0x3F800000u) fv = 1;
    else if (v > 1u) gt1 = 1;
  }
  if (gt1) s_gt1 = 1;
  if (fv)  s_f32 = 1;
  __syncthreads();
  int mode = s_gt1 ? 1 : (s_f32 ? 2 : 0);
  for (int i = t; i < 2048; i += 256) {
    int v;
    if (mode == 1)      v = ((const unsigned char*)raw)[i] ? 1 : 0;
    else if (mode == 2) v = (((const float*)raw)[i] != 0.f) ? 1 : 0;
    else                v = raw[i] ? 1 : 0;
    canon[i] = v;
  }
}

// ---------------------------------------------------------------- layernorm -> f16
__global__ __launch_bounds__(64) void k_ln(const float* __restrict__ s,
                                           const float* __restrict__ gamma,
                                           const float* __restrict__ beta,
                                           unsigned short* __restrict__ sn) {
  int row = blockIdx.x, l = threadIdx.x;
  const float* sr = s + (size_t)row * 512 + l * 8;
  float4 x0 = *(const float4*)sr, x1 = *(const float4*)(sr + 4);
  float sum = x0.x + x0.y + x0.z + x0.w + x1.x + x1.y + x1.z + x1.w;
  float sq  = x0.x*x0.x + x0.y*x0.y + x0.z*x0.z + x0.w*x0.w
            + x1.x*x1.x + x1.y*x1.y + x1.z*x1.z + x1.w*x1.w;
#pragma unroll
  for (int off = 32; off >= 1; off >>= 1) {
    sum += __shfl_xor(sum, off);
    sq  += __shfl_xor(sq, off);
  }
  float mu = sum * (1.f / 512.f);
  float rstd = rsqrtf(sq * (1.f / 512.f) - mu * mu + 1e-5f);
  float4 g0 = *(const float4*)(gamma + l * 8), g1 = *(const float4*)(gamma + l * 8 + 4);
  float4 b0 = *(const float4*)(beta + l * 8),  b1 = *(const float4*)(beta + l * 8 + 4);
  u16x8 o;
  o[0] = f2h((x0.x - mu) * rstd * g0.x + b0.x);
  o[1] = f2h((x0.y - mu) * rstd * g0.y + b0.y);
  o[2] = f2h((x0.z - mu) * rstd * g0.z + b0.z);
  o[3] = f2h((x0.w - mu) * rstd * g0.w + b0.w);
  o[4] = f2h((x1.x - mu) * rstd * g1.x + b1.x);
  o[5] = f2h((x1.y - mu) * rstd * g1.y + b1.y);
  o[6] = f2h((x1.z - mu) * rstd * g1.z + b1.z);
  o[7] = f2h((x1.w - mu) * rstd * g1.w + b1.w);
  *(u16x8*)(sn + (size_t)row * 512 + l * 8) = o;
}

// ---------------------------------------------------------------- GEMM (2048x512x512), f16 MFMA
// A f16 [2048][512], W f32 [512][512].
// mode 0: -> q f16 [row][col] plain     1: -> k f16 [b][h][n][32]
// mode 2: -> v f16 [b][h][d][n]         3: -> gate f32 = sigmoid(.)
// mode 4: -> d_out f32 = gate * (A@W + b)
__global__ __launch_bounds__(256) void k_gemm(const unsigned short* __restrict__ A,
                                              const float* __restrict__ W,
                                              const float* __restrict__ bvec,
                                              void* __restrict__ outp,
                                              const float* __restrict__ gate,
                                              int mode) {
  int ct = blockIdx.x, rt = blockIdx.y;
  int t = threadIdx.x, l = t & 63, w = t >> 6;
  __shared__ unsigned short As[128 * 40];
  __shared__ unsigned short Bs[128 * 40];
  f32x4 acc[4][4];
#pragma unroll
  for (int mt = 0; mt < 4; ++mt)
#pragma unroll
    for (int nt = 0; nt < 4; ++nt) acc[mt][nt] = (f32x4){0.f, 0.f, 0.f, 0.f};

  int arow = t >> 1, akc = (t & 1) * 16;
  int bkk = t >> 3, bc0 = (t & 7) * 16;
  int wr = w >> 1, wc = w & 1;

  for (int k0 = 0; k0 < 512; k0 += 32) {
    const u16x8* ap = (const u16x8*)(A + (size_t)(rt * 128 + arow) * 512 + k0 + akc);
    u16x8 a0 = ap[0], a1 = ap[1];
    *(u16x8*)(&As[arow * 40 + akc]) = a0;
    *(u16x8*)(&As[arow * 40 + akc + 8]) = a1;
    const float* wp = W + (size_t)(k0 + bkk) * 512 + ct * 128 + bc0;
#pragma unroll
    for (int i = 0; i < 4; ++i) {
      float4 f = *(const float4*)(wp + i * 4);
      Bs[(bc0 + i * 4 + 0) * 40 + bkk] = f2h(f.x);
      Bs[(bc0 + i * 4 + 1) * 40 + bkk] = f2h(f.y);
      Bs[(bc0 + i * 4 + 2) * 40 + bkk] = f2h(f.z);
      Bs[(bc0 + i * 4 + 3) * 40 + bkk] = f2h(f.w);
    }
    __syncthreads();
    f16x8 af[4], bf[4];
#pragma unroll
    for (int mt = 0; mt < 4; ++mt)
      af[mt] = *(const f16x8*)(&As[(wr * 64 + mt * 16 + (l & 15)) * 40 + (l >> 4) * 8]);
#pragma unroll
    for (int nt = 0; nt < 4; ++nt)
      bf[nt] = *(const f16x8*)(&Bs[(wc * 64 + nt * 16 + (l & 15)) * 40 + (l >> 4) * 8]);
#pragma unroll
    for (int mt = 0; mt < 4; ++mt)
#pragma unroll
      for (int nt = 0; nt < 4; ++nt)
        acc[mt][nt] = __builtin_amdgcn_mfma_f32_16x16x32_f16(af[mt], bf[nt], acc[mt][nt], 0, 0, 0);
    __syncthreads();
  }

#pragma unroll
  for (int mt = 0; mt < 4; ++mt)
#pragma unroll
    for (int nt = 0; nt < 4; ++nt) {
      int col = ct * 128 + wc * 64 + nt * 16 + (l & 15);
      float bv = bvec[col];
#pragma unroll
      for (int i = 0; i < 4; ++i) {
        int row = rt * 128 + wr * 64 + mt * 16 + (l >> 4) * 4 + i;
        float val = acc[mt][nt][i] + bv;
        int bb_ = row >> 10, n = row & 1023, hh = col >> 5, d = col & 31;
        if (mode == 0) {
          ((unsigned short*)outp)[(size_t)row * 512 + col] = f2h(val);
        } else if (mode == 1) {
          ((unsigned short*)outp)[(((size_t)bb_ * 16 + hh) * 1024 + n) * 32 + d] = f2h(val);
        } else if (mode == 2) {
          ((unsigned short*)outp)[(((size_t)bb_ * 16 + hh) * 32 + d) * 1024 + n] = f2h(val);
        } else if (mode == 3) {
          ((float*)outp)[(size_t)row * 512 + col] = 1.f / (1.f + __expf(-val));
        } else {
          ((float*)outp)[(size_t)row * 512 + col] = gate[(size_t)row * 512 + col] * val;
        }
      }
    }
}

// ---------------------------------------------------------------- fused z-bias + attention
// One block per (b, n). z row streamed once; full-row softmax in LDS.
__global__ __launch_bounds__(256) void k_fused(const __half* __restrict__ q,
                                               const __half* __restrict__ kb,
                                               const __half* __restrict__ vb,
                                               const float* __restrict__ z,
                                               const float* __restrict__ Wb,
                                               const float* __restrict__ bbp,
                                               const int* __restrict__ maskc,
                                               unsigned short* __restrict__ aout) {
  int bid = blockIdx.x;                 // b*1024 + n
  int b = bid >> 10, n = bid & 1023;
  int t = threadIdx.x, l = t & 63, w = t >> 6;
  int hq = l & 15, g = l >> 4;

  __shared__ float sc[1024 * 17 + 16];  // scores [m][17] (col=h); later reused as P f16 [h][1040]

  // Wb B-fragments: lane holds Wb[k=(l>>4)*8+j][h=l&15]
  f16x8 wf[4];
#pragma unroll
  for (int ks = 0; ks < 4; ++ks)
#pragma unroll
    for (int j = 0; j < 8; ++j)
      wf[ks][j] = (_Float16)Wb[(ks * 32 + g * 8 + j) * 16 + hq];
  float bbh = bbp[hq];

  // q row for this lane's head, packed half2 pairs
  unsigned qreg[16];
  const unsigned* qp = (const unsigned*)(q + ((size_t)(b * 1024 + n)) * 512 + hq * 32);
#pragma unroll
  for (int i2 = 0; i2 < 16; ++i2) qreg[i2] = qp[i2];

  const __half* kbase = kb + ((size_t)b * 16 + hq) * 1024 * 32;
  const int* mrow = maskc + b * 1024;
  const float RS = 0.17677669529663687f;  // 1/sqrt(32)

  // ---- Phase A: scores[m][h] = z@Wb + bb + qk/sqrt(32), masked
  for (int j = 0; j < 16; ++j) {
    int m0 = w * 256 + j * 16;
    const float* zp = z + ((size_t)(b * 1024 + n) * 1024 + m0 + hq) * 128 + g * 8;
    f32x4 acc = (f32x4){0.f, 0.f, 0.f, 0.f};
#pragma unroll
    for (int ks = 0; ks < 4; ++ks) {
      float4 z0 = *(const float4*)(zp + ks * 32);
      float4 z1 = *(const float4*)(zp + ks * 32 + 4);
      f16x8 af;
      af[0] = (_Float16)z0.x; af[1] = (_Float16)z0.y;
      af[2] = (_Float16)z0.z; af[3] = (_Float16)z0.w;
      af[4] = (_Float16)z1.x; af[5] = (_Float16)z1.y;
      af[6] = (_Float16)z1.z; af[7] = (_Float16)z1.w;
      acc = __builtin_amdgcn_mfma_f32_16x16x32_f16(af, wf[ks], acc, 0, 0, 0);
    }
    // C layout: col=hq, row=g*4+i -> m
#pragma unroll
    for (int i = 0; i < 4; ++i) {
      int m = m0 + g * 4 + i;
      const uint4* kr = (const uint4*)(kbase + (size_t)m * 32);
      uint4 k0 = kr[0], k1 = kr[1], k2 = kr[2], k3 = kr[3];
      float dot = 0.f;
      dot = fdot2u(k0.x, qreg[0], dot);  dot = fdot2u(k0.y, qreg[1], dot);
      dot = fdot2u(k0.z, qreg[2], dot);  dot = fdot2u(k0.w, qreg[3], dot);
      dot = fdot2u(k1.x, qreg[4], dot);  dot = fdot2u(k1.y, qreg[5], dot);
      dot = fdot2u(k1.z, qreg[6], dot);  dot = fdot2u(k1.w, qreg[7], dot);
      dot = fdot2u(k2.x, qreg[8], dot);  dot = fdot2u(k2.y, qreg[9], dot);
      dot = fdot2u(k2.z, qreg[10], dot); dot = fdot2u(k2.w, qreg[11], dot);
      dot = fdot2u(k3.x, qreg[12], dot); dot = fdot2u(k3.y, qreg[13], dot);
      dot = fdot2u(k3.z, qreg[14], dot); dot = fdot2u(k3.w, qreg[15], dot);
      float sval = acc[i] + bbh + dot * RS;
      sc[m * 17 + hq] = mrow[m] ? -1e30f : sval;
    }
  }
  __syncthreads();

  // ---- Phase B: softmax per head; wave w owns h = 4w..4w+3
  float vals[4][16];
#pragma unroll
  for (int hs = 0; hs < 4; ++hs) {
    int h = w * 4 + hs;
#pragma unroll
    for (int j2 = 0; j2 < 16; ++j2)
      vals[hs][j2] = sc[(l + 64 * j2) * 17 + h];
  }
  __syncthreads();  // all score reads done; sc region now reusable as P

  unsigned short* P = (unsigned short*)sc;  // P[h][1040] f16 (normalized)
#pragma unroll
  for (int hs = 0; hs < 4; ++hs) {
    int h = w * 4 + hs;
    float mx = -3.4e38f;
#pragma unroll
    for (int j2 = 0; j2 < 16; ++j2) mx = fmaxf(mx, vals[hs][j2]);
#pragma unroll
    for (int off = 32; off >= 1; off >>= 1) mx = fmaxf(mx, __shfl_xor(mx, off));
    float sum = 0.f;
#pragma unroll
    for (int j2 = 0; j2 < 16; ++j2) {
      float e = __expf(vals[hs][j2] - mx);
      vals[hs][j2] = e;
      sum += e;
    }
#pragma unroll
    for (int off = 32; off >= 1; off >>= 1) sum += __shfl_xor(sum, off);
    float inv = (sum > 0.f) ? 1.f / sum : 0.f;
#pragma unroll
    for (int j2 = 0; j2 < 16; ++j2)
      P[h * 1040 + l + 64 * j2] = f2h(vals[hs][j2] * inv);
  }
  __syncthreads();

  // ---- Phase C: out[h][d] = sum_m P[h][m] * v[h][d][m]
  {
    int h = w * 4 + (l >> 4);
    int d0 = (l & 15) * 2;
    const uint4* Pp = (const uint4*)(P + h * 1040);
    const uint4* v0p = (const uint4*)(vb + (((size_t)b * 16 + h) * 32 + d0) * 1024);
    const uint4* v1p = (const uint4*)(vb + (((size_t)b * 16 + h) * 32 + d0 + 1) * 1024);
    float a0 = 0.f, a1 = 0.f;
    for (int mc = 0; mc < 128; ++mc) {
      uint4 pq = Pp[mc];
      uint4 va = v0p[mc];
      uint4 vb2 = v1p[mc];
      a0 = fdot2u(pq.x, va.x, a0);  a0 = fdot2u(pq.y, va.y, a0);
      a0 = fdot2u(pq.z, va.z, a0);  a0 = fdot2u(pq.w, va.w, a0);
      a1 = fdot2u(pq.x, vb2.x, a1); a1 = fdot2u(pq.y, vb2.y, a1);
      a1 = fdot2u(pq.z, vb2.z, a1); a1 = fdot2u(pq.w, vb2.w, a1);
    }
    unsigned packed = (unsigned)f2h(a0) | ((unsigned)f2h(a1) << 16);
    *(unsigned*)(aout + ((size_t)(b * 1024 + n)) * 512 + h * 32 + d0) = packed;
  }
}

// ----------------------------------------------------------------
extern "C" void kernel_launch(void* const* d_in, const int* in_sizes, int n_in,
                              void* d_out, int out_size, void* d_ws, size_t ws_size,
                              hipStream_t stream) {
  (void)in_sizes; (void)n_in; (void)out_size; (void)ws_size;
  const float* s     = (const float*)d_in[0];
  const float* z     = (const float*)d_in[1];
  const unsigned* km = (const unsigned*)d_in[2];
  const float* Wq = (const float*)d_in[3];
  const float* bq = (const float*)d_in[4];
  const float* Wk = (const float*)d_in[5];
  const float* bk = (const float*)d_in[6];
  const float* Wv = (const float*)d_in[7];
  const float* bv = (const float*)d_in[8];
  const float* Wb = (const float*)d_in[9];
  const float* bb = (const float*)d_in[10];
  const float* Wg = (const float*)d_in[11];
  const float* bg = (const float*)d_in[12];
  const float* Wo = (const float*)d_in[13];
  const float* bo = (const float*)d_in[14];
  const float* gamma = (const float*)d_in[15];
  const float* beta  = (const float*)d_in[16];

  char* ws = (char*)d_ws;
  unsigned short* sn    = (unsigned short*)(ws);                // 2 MB f16
  unsigned short* qbuf  = (unsigned short*)(ws + (2ull << 20)); // 2 MB f16 [b][n][512]
  unsigned short* kbuf  = (unsigned short*)(ws + (4ull << 20)); // 2 MB f16 [b][h][n][32]
  unsigned short* vbuf  = (unsigned short*)(ws + (6ull << 20)); // 2 MB f16 [b][h][d][n]
  float*          gate  = (float*)(ws + (8ull << 20));          // 4 MB f32
  unsigned short* aout  = (unsigned short*)(ws + (12ull << 20));// 2 MB f16
  int*            maskc = (int*)(ws + (14ull << 20));           // 8 KB

  hipLaunchKernelGGL(k_mask, dim3(1), dim3(256), 0, stream, km, maskc);
  hipLaunchKernelGGL(k_ln, dim3(2048), dim3(64), 0, stream, s, gamma, beta, sn);
  dim3 g2(4, 16);
  hipLaunchKernelGGL(k_gemm, g2, dim3(256), 0, stream, sn, Wq, bq, (void*)qbuf, (const float*)nullptr, 0);
  hipLaunchKernelGGL(k_gemm, g2, dim3(256), 0, stream, sn, Wk, bk, (void*)kbuf, (const float*)nullptr, 1);
  hipLaunchKernelGGL(k_gemm, g2, dim3(256), 0, stream, sn, Wv, bv, (void*)vbuf, (const float*)nullptr, 2);
  hipLaunchKernelGGL(k_gemm, g2, dim3(256), 0, stream, sn, Wg, bg, (void*)gate, (const float*)nullptr, 3);
  hipLaunchKernelGGL(k_fused, dim3(2048), dim3(256), 0, stream,
                     (const __half*)qbuf, (const __half*)kbuf, (const __half*)vbuf,
                     z, Wb, bb, maskc, aout);
  hipLaunchKernelGGL(k_gemm, g2, dim3(256), 0, stream, aout, Wo, bo, d_out, gate, 4);
}

// Round 3
// 352.618 us; speedup vs baseline: 2.3502x; 2.3502x over previous
//
#include <hip/hip_runtime.h>
#include <hip/hip_fp16.h>

typedef __attribute__((ext_vector_type(8))) _Float16 f16x8;
typedef __attribute__((ext_vector_type(8))) unsigned short u16x8;
typedef __attribute__((ext_vector_type(4))) float f32x4;

#define DEV __device__ __forceinline__

DEV unsigned short f2h(float f) {
  _Float16 h = (_Float16)f;
  return __builtin_bit_cast(unsigned short, h);
}
DEV float h2f(unsigned short u) {
  return (float)__builtin_bit_cast(_Float16, u);
}
DEV unsigned pk(float lo, float hi) {
  return (unsigned)f2h(lo) | ((unsigned)f2h(hi) << 16);
}

// ---------------------------------------------------------------- mask canon
__global__ __launch_bounds__(256) void k_mask(const unsigned* __restrict__ raw,
                                              int* __restrict__ canon) {
  __shared__ int s_gt1, s_f32;
  int t = threadIdx.x;
  if (t == 0) { s_gt1 = 0; s_f32 = 0; }
  __syncthreads();
  int gt1 = 0, fv = 0;
  for (int i = t; i < 512; i += 256) {
    unsigned v = raw[i];
    if (v == 0x3F800000u) fv = 1;
    else if (v > 1u) gt1 = 1;
  }
  if (gt1) s_gt1 = 1;
  if (fv)  s_f32 = 1;
  __syncthreads();
  int mode = s_gt1 ? 1 : (s_f32 ? 2 : 0);
  for (int i = t; i < 2048; i += 256) {
    int v;
    if (mode == 1)      v = ((const unsigned char*)raw)[i] ? 1 : 0;
    else if (mode == 2) v = (((const float*)raw)[i] != 0.f) ? 1 : 0;
    else                v = raw[i] ? 1 : 0;
    canon[i] = v;
  }
}

// ---------------------------------------------------------------- layernorm -> f16
__global__ __launch_bounds__(64) void k_ln(const float* __restrict__ s,
                                           const float* __restrict__ gamma,
                                           const float* __restrict__ beta,
                                           unsigned short* __restrict__ sn) {
  int row = blockIdx.x, l = threadIdx.x;
  const float* sr = s + (size_t)row * 512 + l * 8;
  float4 x0 = *(const float4*)sr, x1 = *(const float4*)(sr + 4);
  float sum = x0.x + x0.y + x0.z + x0.w + x1.x + x1.y + x1.z + x1.w;
  float sq  = x0.x*x0.x + x0.y*x0.y + x0.z*x0.z + x0.w*x0.w
            + x1.x*x1.x + x1.y*x1.y + x1.z*x1.z + x1.w*x1.w;
#pragma unroll
  for (int off = 32; off >= 1; off >>= 1) {
    sum += __shfl_xor(sum, off);
    sq  += __shfl_xor(sq, off);
  }
  float mu = sum * (1.f / 512.f);
  float rstd = rsqrtf(sq * (1.f / 512.f) - mu * mu + 1e-5f);
  float4 g0 = *(const float4*)(gamma + l * 8), g1 = *(const float4*)(gamma + l * 8 + 4);
  float4 b0 = *(const float4*)(beta + l * 8),  b1 = *(const float4*)(beta + l * 8 + 4);
  u16x8 o;
  o[0] = f2h((x0.x - mu) * rstd * g0.x + b0.x);
  o[1] = f2h((x0.y - mu) * rstd * g0.y + b0.y);
  o[2] = f2h((x0.z - mu) * rstd * g0.z + b0.z);
  o[3] = f2h((x0.w - mu) * rstd * g0.w + b0.w);
  o[4] = f2h((x1.x - mu) * rstd * g1.x + b1.x);
  o[5] = f2h((x1.y - mu) * rstd * g1.y + b1.y);
  o[6] = f2h((x1.z - mu) * rstd * g1.z + b1.z);
  o[7] = f2h((x1.w - mu) * rstd * g1.w + b1.w);
  *(u16x8*)(sn + (size_t)row * 512 + l * 8) = o;
}

// ---------------------------------------------------------------- GEMM body (2048x512x512)
// mode 0: q f16 [row][col]  1: k f16 [b][h][m][d]  2: v f16 [b][h][d][m]
// mode 3: gate f32 sigmoid  4: d_out f32 = gate * (A@W + b)
DEV void gemm_body(const unsigned short* __restrict__ A,
                   const float* __restrict__ W,
                   const float* __restrict__ bvec,
                   void* __restrict__ outp,
                   const float* __restrict__ gate,
                   int mode, int ct, int rt) {
  int t = threadIdx.x, l = t & 63, w = t >> 6;
  __shared__ unsigned short As[128 * 40];
  __shared__ unsigned short Bs[128 * 40];
  f32x4 acc[4][4];
#pragma unroll
  for (int mt = 0; mt < 4; ++mt)
#pragma unroll
    for (int nt = 0; nt < 4; ++nt) acc[mt][nt] = (f32x4){0.f, 0.f, 0.f, 0.f};

  int arow = t >> 1, akc = (t & 1) * 16;
  int bkk = t >> 3, bc0 = (t & 7) * 16;
  int wr = w >> 1, wc = w & 1;

  for (int k0 = 0; k0 < 512; k0 += 32) {
    const u16x8* ap = (const u16x8*)(A + (size_t)(rt * 128 + arow) * 512 + k0 + akc);
    u16x8 a0 = ap[0], a1 = ap[1];
    *(u16x8*)(&As[arow * 40 + akc]) = a0;
    *(u16x8*)(&As[arow * 40 + akc + 8]) = a1;
    const float* wp = W + (size_t)(k0 + bkk) * 512 + ct * 128 + bc0;
#pragma unroll
    for (int i = 0; i < 4; ++i) {
      float4 f = *(const float4*)(wp + i * 4);
      Bs[(bc0 + i * 4 + 0) * 40 + bkk] = f2h(f.x);
      Bs[(bc0 + i * 4 + 1) * 40 + bkk] = f2h(f.y);
      Bs[(bc0 + i * 4 + 2) * 40 + bkk] = f2h(f.z);
      Bs[(bc0 + i * 4 + 3) * 40 + bkk] = f2h(f.w);
    }
    __syncthreads();
    f16x8 af[4], bf[4];
#pragma unroll
    for (int mt = 0; mt < 4; ++mt)
      af[mt] = *(const f16x8*)(&As[(wr * 64 + mt * 16 + (l & 15)) * 40 + (l >> 4) * 8]);
#pragma unroll
    for (int nt = 0; nt < 4; ++nt)
      bf[nt] = *(const f16x8*)(&Bs[(wc * 64 + nt * 16 + (l & 15)) * 40 + (l >> 4) * 8]);
#pragma unroll
    for (int mt = 0; mt < 4; ++mt)
#pragma unroll
      for (int nt = 0; nt < 4; ++nt)
        acc[mt][nt] = __builtin_amdgcn_mfma_f32_16x16x32_f16(af[mt], bf[nt], acc[mt][nt], 0, 0, 0);
    __syncthreads();
  }

#pragma unroll
  for (int mt = 0; mt < 4; ++mt)
#pragma unroll
    for (int nt = 0; nt < 4; ++nt) {
      int col = ct * 128 + wc * 64 + nt * 16 + (l & 15);
      float bv = bvec[col];
#pragma unroll
      for (int i = 0; i < 4; ++i) {
        int row = rt * 128 + wr * 64 + mt * 16 + (l >> 4) * 4 + i;
        float val = acc[mt][nt][i] + bv;
        int bb_ = row >> 10, n = row & 1023, hh = col >> 5, d = col & 31;
        if (mode == 0) {
          ((unsigned short*)outp)[(size_t)row * 512 + col] = f2h(val);
        } else if (mode == 1) {
          ((unsigned short*)outp)[(((size_t)bb_ * 16 + hh) * 1024 + n) * 32 + d] = f2h(val);
        } else if (mode == 2) {
          ((unsigned short*)outp)[(((size_t)bb_ * 16 + hh) * 32 + d) * 1024 + n] = f2h(val);
        } else if (mode == 3) {
          ((float*)outp)[(size_t)row * 512 + col] = 1.f / (1.f + __expf(-val));
        } else {
          ((float*)outp)[(size_t)row * 512 + col] = gate[(size_t)row * 512 + col] * val;
        }
      }
    }
}

__global__ __launch_bounds__(256) void k_qkvg(const unsigned short* __restrict__ A,
                                              const float* __restrict__ W0, const float* __restrict__ W1,
                                              const float* __restrict__ W2, const float* __restrict__ W3,
                                              const float* __restrict__ b0, const float* __restrict__ b1,
                                              const float* __restrict__ b2, const float* __restrict__ b3,
                                              void* o0, void* o1, void* o2, void* o3) {
  int mode = blockIdx.z;
  const float* W = (mode == 0) ? W0 : (mode == 1) ? W1 : (mode == 2) ? W2 : W3;
  const float* bv = (mode == 0) ? b0 : (mode == 1) ? b1 : (mode == 2) ? b2 : b3;
  void* o = (mode == 0) ? o0 : (mode == 1) ? o1 : (mode == 2) ? o2 : o3;
  gemm_body(A, W, bv, o, nullptr, mode, blockIdx.x, blockIdx.y);
}

__global__ __launch_bounds__(256) void k_gemm_out(const unsigned short* __restrict__ A,
                                                  const float* __restrict__ W,
                                                  const float* __restrict__ bvec,
                                                  float* __restrict__ outp,
                                                  const float* __restrict__ gate) {
  gemm_body(A, W, bvec, outp, gate, 4, blockIdx.x, blockIdx.y);
}

// ---------------------------------------------------------------- pair-bias stream
// bias[b][n][h][m] f16 = z[b,n,m,:]@Wb[:,h] + bb[h]; masked m -> -65504.
// One block per (b,n); 8 waves x 128 m-rows; zero LDS; pure streaming.
__global__ __launch_bounds__(512) void k_bias(const float* __restrict__ z,
                                              const float* __restrict__ Wb,
                                              const float* __restrict__ bbp,
                                              const int* __restrict__ maskc,
                                              unsigned short* __restrict__ bias) {
  int bid = blockIdx.x;             // b*1024 + n
  int b = bid >> 10;
  int t = threadIdx.x, l = t & 63, w = t >> 6;
  int lane15 = l & 15, g = l >> 4;  // lane15: A-row within tile AND head col

  // B-frag: lane holds Wb[k=ks*32+g*8+j][h=lane15]
  f16x8 wf[4];
#pragma unroll
  for (int ks = 0; ks < 4; ++ks)
#pragma unroll
    for (int j = 0; j < 8; ++j)
      wf[ks][j] = (_Float16)Wb[(ks * 32 + g * 8 + j) * 16 + lane15];
  float bbh = bbp[lane15];

  const float* zb = z + (size_t)bid * (1024 * 128);
  unsigned short* ob = bias + ((size_t)bid * 16 + lane15) * 1024;
  const int* mrow = maskc + b * 1024;

#pragma unroll 2
  for (int mt = 0; mt < 8; ++mt) {
    int m0 = w * 128 + mt * 16;
    const float* zr = zb + (size_t)(m0 + lane15) * 128 + g * 8;
    f32x4 acc = (f32x4){0.f, 0.f, 0.f, 0.f};
#pragma unroll
    for (int ks = 0; ks < 4; ++ks) {
      float4 z0 = *(const float4*)(zr + ks * 32);
      float4 z1 = *(const float4*)(zr + ks * 32 + 4);
      f16x8 af;
      af[0] = (_Float16)z0.x; af[1] = (_Float16)z0.y;
      af[2] = (_Float16)z0.z; af[3] = (_Float16)z0.w;
      af[4] = (_Float16)z1.x; af[5] = (_Float16)z1.y;
      af[6] = (_Float16)z1.z; af[7] = (_Float16)z1.w;
      acc = __builtin_amdgcn_mfma_f32_16x16x32_f16(af, wf[ks], acc, 0, 0, 0);
    }
    // C: col=h=lane15, row=m-in-tile=4g+i
    int m = m0 + 4 * g;
    int4 mk = *(const int4*)(mrow + m);
    ushort4 o4;
    o4.x = mk.x ? 0xFBFFu : f2h(acc[0] + bbh);
    o4.y = mk.y ? 0xFBFFu : f2h(acc[1] + bbh);
    o4.z = mk.z ? 0xFBFFu : f2h(acc[2] + bbh);
    o4.w = mk.w ? 0xFBFFu : f2h(acc[3] + bbh);
    *(ushort4*)(ob + m) = o4;
  }
}

// ---------------------------------------------------------------- attention (in-register flash)
// Block: (qt, h, b); 4 waves x 16 q-rows. Swapped QK^T (lane owns col q), online
// softmax across lane-groups via shfl_xor, P repacked to PV B-frag via shfl.
__global__ __launch_bounds__(256, 4) void k_attn(const unsigned short* __restrict__ qbuf,
                                                 const unsigned short* __restrict__ kbuf,
                                                 const unsigned short* __restrict__ vbuf,
                                                 const unsigned short* __restrict__ bias,
                                                 unsigned short* __restrict__ aout) {
  int qt = blockIdx.x, h = blockIdx.y, b = blockIdx.z;
  int t = threadIdx.x, l = t & 63, w = t >> 6;
  int q0 = (qt * 4 + w) * 16;
  int lane15 = l & 15, g = l >> 4;
  int bh = b * 16 + h;
  const float RS = 0.17677669529663687f;  // 1/sqrt(32)

  // Q B-frag: lane holds Q[q0+lane15][d=g*8+j]
  f16x8 qf = *(const f16x8*)(qbuf + ((size_t)(b * 1024 + q0 + lane15)) * 512 + h * 32 + g * 8);

  const unsigned short* kb_ = kbuf + (size_t)bh * 1024 * 32;
  const unsigned short* vb_ = vbuf + (size_t)bh * 32 * 1024;
  const unsigned short* brow = bias + ((size_t)(b * 1024 + q0 + lane15) * 16 + h) * 1024;

  float m_run = -3.0e38f, lsum = 0.f;
  f32x4 acc1 = (f32x4){0.f, 0.f, 0.f, 0.f};
  f32x4 acc2 = (f32x4){0.f, 0.f, 0.f, 0.f};

  for (int c = 0; c < 32; ++c) {
    int m0 = c * 32;
    // QK^T swapped: A=K rows m, B=Q cols q -> C[row=m-in-tile][col=q]
    f16x8 kf1 = *(const f16x8*)(kb_ + (size_t)(m0 + lane15) * 32 + g * 8);
    f16x8 kf2 = *(const f16x8*)(kb_ + (size_t)(m0 + 16 + lane15) * 32 + g * 8);
    f32x4 zero = (f32x4){0.f, 0.f, 0.f, 0.f};
    f32x4 c1 = __builtin_amdgcn_mfma_f32_16x16x32_f16(kf1, qf, zero, 0, 0, 0);
    f32x4 c2 = __builtin_amdgcn_mfma_f32_16x16x32_f16(kf2, qf, zero, 0, 0, 0);
    // bias (mask pre-baked): lane q=lane15 holds m = m0+4g+i and +16
    ushort4 bv1 = *(const ushort4*)(brow + m0 + 4 * g);
    ushort4 bv2 = *(const ushort4*)(brow + m0 + 16 + 4 * g);
    float s1[4], s2[4];
    s1[0] = c1[0] * RS + h2f(bv1.x); s1[1] = c1[1] * RS + h2f(bv1.y);
    s1[2] = c1[2] * RS + h2f(bv1.z); s1[3] = c1[3] * RS + h2f(bv1.w);
    s2[0] = c2[0] * RS + h2f(bv2.x); s2[1] = c2[1] * RS + h2f(bv2.y);
    s2[2] = c2[2] * RS + h2f(bv2.z); s2[3] = c2[3] * RS + h2f(bv2.w);
    // chunk max over this lane's 8, then over the 4 lane-groups (same q)
    float cm = fmaxf(fmaxf(fmaxf(s1[0], s1[1]), fmaxf(s1[2], s1[3])),
                     fmaxf(fmaxf(s2[0], s2[1]), fmaxf(s2[2], s2[3])));
    cm = fmaxf(cm, __shfl_xor(cm, 16));
    cm = fmaxf(cm, __shfl_xor(cm, 32));
    float mn = fmaxf(m_run, cm);
    float corr = __expf(m_run - mn);
    m_run = mn;
    float p1[4], p2[4], csum = 0.f;
#pragma unroll
    for (int i = 0; i < 4; ++i) { p1[i] = __expf(s1[i] - mn); csum += p1[i]; }
#pragma unroll
    for (int i = 0; i < 4; ++i) { p2[i] = __expf(s2[i] - mn); csum += p2[i]; }
    lsum = lsum * corr + csum;
#pragma unroll
    for (int i = 0; i < 4; ++i) { acc1[i] *= corr; acc2[i] *= corr; }
    // repack P (C-layout) -> PV B-frag: dst lane (q,g) wants m=m0+8g..8g+7:
    //   pairs from src lanes s0=32*(g&1)+q (j0..3) and s0+16 (j4..7),
    //   taken from C1 if g<2 else C2.
    unsigned a0 = pk(p1[0], p1[1]), a1 = pk(p1[2], p1[3]);
    unsigned b0 = pk(p2[0], p2[1]), b1 = pk(p2[2], p2[3]);
    int s0 = ((g & 1) << 5) + lane15, s1l = s0 + 16;
    unsigned wA0 = (unsigned)__shfl((int)a0, s0);
    unsigned wA1 = (unsigned)__shfl((int)a1, s0);
    unsigned wA2 = (unsigned)__shfl((int)a0, s1l);
    unsigned wA3 = (unsigned)__shfl((int)a1, s1l);
    unsigned wB0 = (unsigned)__shfl((int)b0, s0);
    unsigned wB1 = (unsigned)__shfl((int)b1, s0);
    unsigned wB2 = (unsigned)__shfl((int)b0, s1l);
    unsigned wB3 = (unsigned)__shfl((int)b1, s1l);
    bool hi = (l & 32) != 0;
    union { unsigned u[4]; f16x8 v; } pu;
    pu.u[0] = hi ? wB0 : wA0;
    pu.u[1] = hi ? wB1 : wA1;
    pu.u[2] = hi ? wB2 : wA2;
    pu.u[3] = hi ? wB3 : wA3;
    // PV: A = V^T (row=d, k=m), B = P^T -> C[row=d-in-tile][col=q]
    f16x8 vf1 = *(const f16x8*)(vb_ + (size_t)lane15 * 1024 + m0 + 8 * g);
    f16x8 vf2 = *(const f16x8*)(vb_ + (size_t)(16 + lane15) * 1024 + m0 + 8 * g);
    acc1 = __builtin_amdgcn_mfma_f32_16x16x32_f16(vf1, pu.v, acc1, 0, 0, 0);
    acc2 = __builtin_amdgcn_mfma_f32_16x16x32_f16(vf2, pu.v, acc2, 0, 0, 0);
  }

  lsum += __shfl_xor(lsum, 16);
  lsum += __shfl_xor(lsum, 32);
  // all-keys-masked row => m_run ~ -65500 => output 0 (matches nan_to_num)
  float inv = (m_run > -30000.f && lsum > 0.f) ? 1.f / lsum : 0.f;
  unsigned short* orow = aout + ((size_t)(b * 1024 + q0 + lane15)) * 512 + h * 32;
  ushort4 o1, o2;
  o1.x = f2h(acc1[0] * inv); o1.y = f2h(acc1[1] * inv);
  o1.z = f2h(acc1[2] * inv); o1.w = f2h(acc1[3] * inv);
  o2.x = f2h(acc2[0] * inv); o2.y = f2h(acc2[1] * inv);
  o2.z = f2h(acc2[2] * inv); o2.w = f2h(acc2[3] * inv);
  *(ushort4*)(orow + 4 * g) = o1;
  *(ushort4*)(orow + 16 + 4 * g) = o2;
}

// ----------------------------------------------------------------
extern "C" void kernel_launch(void* const* d_in, const int* in_sizes, int n_in,
                              void* d_out, int out_size, void* d_ws, size_t ws_size,
                              hipStream_t stream) {
  (void)in_sizes; (void)n_in; (void)out_size; (void)ws_size;
  const float* s     = (const float*)d_in[0];
  const float* z     = (const float*)d_in[1];
  const unsigned* km = (const unsigned*)d_in[2];
  const float* Wq = (const float*)d_in[3];
  const float* bq = (const float*)d_in[4];
  const float* Wk = (const float*)d_in[5];
  const float* bk = (const float*)d_in[6];
  const float* Wv = (const float*)d_in[7];
  const float* bv = (const float*)d_in[8];
  const float* Wb = (const float*)d_in[9];
  const float* bb = (const float*)d_in[10];
  const float* Wg = (const float*)d_in[11];
  const float* bg = (const float*)d_in[12];
  const float* Wo = (const float*)d_in[13];
  const float* bo = (const float*)d_in[14];
  const float* gamma = (const float*)d_in[15];
  const float* beta  = (const float*)d_in[16];

  char* ws = (char*)d_ws;
  unsigned short* sn    = (unsigned short*)(ws);                 // 2 MB
  unsigned short* qbuf  = (unsigned short*)(ws + (2ull << 20));  // 2 MB [b n][512]
  unsigned short* kbuf  = (unsigned short*)(ws + (4ull << 20));  // 2 MB [b][h][m][d]
  unsigned short* vbuf  = (unsigned short*)(ws + (6ull << 20));  // 2 MB [b][h][d][m]
  float*          gate  = (float*)(ws + (8ull << 20));           // 4 MB
  unsigned short* aout  = (unsigned short*)(ws + (12ull << 20)); // 2 MB
  unsigned short* bias  = (unsigned short*)(ws + (14ull << 20)); // 64 MB [b][n][h][m]
  int*            maskc = (int*)(ws + (78ull << 20));            // 8 KB

  hipLaunchKernelGGL(k_mask, dim3(1), dim3(256), 0, stream, km, maskc);
  hipLaunchKernelGGL(k_ln, dim3(2048), dim3(64), 0, stream, s, gamma, beta, sn);
  hipLaunchKernelGGL(k_qkvg, dim3(4, 16, 4), dim3(256), 0, stream, sn,
                     Wq, Wk, Wv, Wg, bq, bk, bv, bg,
                     (void*)qbuf, (void*)kbuf, (void*)vbuf, (void*)gate);
  hipLaunchKernelGGL(k_bias, dim3(2048), dim3(512), 0, stream, z, Wb, bb, maskc, bias);
  hipLaunchKernelGGL(k_attn, dim3(16, 16, 2), dim3(256), 0, stream,
                     qbuf, kbuf, vbuf, bias, aout);
  hipLaunchKernelGGL(k_gemm_out, dim3(4, 16), dim3(256), 0, stream, aout, Wo, bo,
                     (float*)d_out, gate);
}